// Round 1
// baseline (234.922 us; speedup 1.0000x reference)
//
#include <hip/hip_runtime.h>

// Round 1: fp16 MFMA flash attention.
//   d_in order: 0=x [4,4096,256] f32, 1=mask [4,4096] i32, 2=Wk, 3=Wq, 4=Wv [256,256] f32
//   out: [4,4096,256] f32
// ws layout: q fp16 [B*T][C] (pre-scaled by 1/16), k fp16 [B*T][C], vt fp16 [B][C][T]

typedef __attribute__((ext_vector_type(8))) _Float16 f16x8;
typedef __attribute__((ext_vector_type(4))) _Float16 f16x4;
typedef __attribute__((ext_vector_type(4))) float    f32x4;

constexpr int Bb = 4;
constexpr int Tt = 4096;
constexpr int Cc = 256;
constexpr int BT = Bb * Tt;

#define MFMA(a, b, c) __builtin_amdgcn_mfma_f32_16x16x32_f16((a), (b), (c), 0, 0, 0)

// ---------------- Kernel A: fused QKV projection (y = x @ W^T) ----------------
// grid (128, 6): x-tile 128 rows, y: 0,1=q  2,3=k  4,5=v (d0 = (y&1)*128)
__global__ __launch_bounds__(256) void qkv_proj(
    const float* __restrict__ x,
    const float* __restrict__ Wq, const float* __restrict__ Wk,
    const float* __restrict__ Wv,
    _Float16* __restrict__ qo, _Float16* __restrict__ ko,
    _Float16* __restrict__ vto)
{
    extern __shared__ _Float16 sm[];
    _Float16* xs = sm;              // [128][264]  (pad 8)
    _Float16* wsm = sm + 128 * 264; // [128][264]

    const int tid = threadIdx.x;
    const int m0  = blockIdx.x * 128;
    const int ny  = blockIdx.y;
    const int mat = ny >> 1;              // 0=q 1=k 2=v
    const int d0  = (ny & 1) * 128;
    const float* W = (mat == 0) ? Wq : (mat == 1 ? Wk : Wv);

    // stage x tile (f32 -> f16): 128x256
#pragma unroll
    for (int i = 0; i < 32; ++i) {
        int flat = i * 256 + tid;
        int r = flat >> 6, c4 = (flat & 63) << 2;
        float4 v = *reinterpret_cast<const float4*>(x + (size_t)(m0 + r) * Cc + c4);
        f16x4 h = { (_Float16)v.x, (_Float16)v.y, (_Float16)v.z, (_Float16)v.w };
        *reinterpret_cast<f16x4*>(xs + r * 264 + c4) = h;
    }
    // stage W tile: 128x256
#pragma unroll
    for (int i = 0; i < 32; ++i) {
        int flat = i * 256 + tid;
        int r = flat >> 6, c4 = (flat & 63) << 2;
        float4 v = *reinterpret_cast<const float4*>(W + (size_t)(d0 + r) * Cc + c4);
        f16x4 h = { (_Float16)v.x, (_Float16)v.y, (_Float16)v.z, (_Float16)v.w };
        *reinterpret_cast<f16x4*>(wsm + r * 264 + c4) = h;
    }
    __syncthreads();

    const int w = tid >> 6, lane = tid & 63;
    const int lr = lane & 15, lg = lane >> 4;

    f32x4 acc[2][8] = {};   // [m-block][d-block]

#pragma unroll
    for (int kc = 0; kc < 8; ++kc) {
        const int c0 = kc * 32 + lg * 8;
        f16x8 xf[2], wf[8];
#pragma unroll
        for (int mb = 0; mb < 2; ++mb)
            xf[mb] = *reinterpret_cast<const f16x8*>(xs + (w * 32 + mb * 16 + lr) * 264 + c0);
#pragma unroll
        for (int db = 0; db < 8; ++db)
            wf[db] = *reinterpret_cast<const f16x8*>(wsm + (db * 16 + lr) * 264 + c0);
        if (mat != 2) {
            // swapped: D[d][m] -> lane holds 4 consecutive d for fixed m (contiguous q/k store)
#pragma unroll
            for (int mb = 0; mb < 2; ++mb)
#pragma unroll
                for (int db = 0; db < 8; ++db)
                    acc[mb][db] = MFMA(wf[db], xf[mb], acc[mb][db]);
        } else {
            // normal: D[m][d] -> lane holds 4 consecutive m for fixed d (contiguous vt store)
#pragma unroll
            for (int mb = 0; mb < 2; ++mb)
#pragma unroll
                for (int db = 0; db < 8; ++db)
                    acc[mb][db] = MFMA(xf[mb], wf[db], acc[mb][db]);
        }
    }

    if (mat != 2) {
        const float sc = (mat == 0) ? 0.0625f : 1.0f;   // fold 1/sqrt(256) into q
        _Float16* dst = (mat == 0) ? qo : ko;
#pragma unroll
        for (int mb = 0; mb < 2; ++mb)
#pragma unroll
            for (int db = 0; db < 8; ++db) {
                int m = m0 + w * 32 + mb * 16 + lr;
                int d = d0 + db * 16 + lg * 4;
                f32x4 a = acc[mb][db];
                f16x4 h = { (_Float16)(a.x * sc), (_Float16)(a.y * sc),
                            (_Float16)(a.z * sc), (_Float16)(a.w * sc) };
                *reinterpret_cast<f16x4*>(dst + (size_t)m * Cc + d) = h;
            }
    } else {
#pragma unroll
        for (int mb = 0; mb < 2; ++mb)
#pragma unroll
            for (int db = 0; db < 8; ++db) {
                int d = d0 + db * 16 + lr;
                int m = m0 + w * 32 + mb * 16 + lg * 4;
                int bb = m >> 12, t = m & (Tt - 1);
                f32x4 a = acc[mb][db];
                f16x4 h = { (_Float16)a.x, (_Float16)a.y, (_Float16)a.z, (_Float16)a.w };
                *reinterpret_cast<f16x4*>(vto + (size_t)bb * Cc * Tt + (size_t)d * Tt + t) = h;
            }
    }
}

// ---------------- Kernel B: flash attention ----------------
// grid (T/64, B), 4 waves; wave owns 16 query rows; key tiles of 64
__global__ __launch_bounds__(256) void attn_kernel(
    const _Float16* __restrict__ qb, const _Float16* __restrict__ kb,
    const _Float16* __restrict__ vtb, const int* __restrict__ mask,
    float* __restrict__ out)
{
    extern __shared__ _Float16 sm[];
    _Float16* ksm = sm;                  // [64][264]  K tile (pad 8)
    _Float16* vts = sm + 64 * 264;       // [256][72]  V^T tile (pad 8)
    _Float16* ps  = vts + 256 * 72;      // [4][16][72] per-wave P transpose buffer

    const int tid = threadIdx.x, w = tid >> 6, lane = tid & 63;
    const int lr = lane & 15, lg = lane >> 4;
    const int b  = blockIdx.y;
    const int q0 = blockIdx.x * 64;
    const size_t base = (size_t)b * Tt * Cc;

    // load Q fragments once (A-layout: row = lane&15, k = lg*8+j)
    f16x8 qf[8];
    {
        const _Float16* qp = qb + base + (size_t)(q0 + w * 16 + lr) * Cc;
#pragma unroll
        for (int kc = 0; kc < 8; ++kc)
            qf[kc] = *reinterpret_cast<const f16x8*>(qp + kc * 32 + lg * 8);
    }

    f32x4 o[16] = {};                       // O accumulator: 16 d-blocks
    float m_run[4] = { -1e30f, -1e30f, -1e30f, -1e30f };
    float l_run[4] = { 0.f, 0.f, 0.f, 0.f };

    for (int kt = 0; kt < 64; ++kt) {
        const int k0 = kt * 64;
        __syncthreads();   // all waves done reading previous tile
        // stage K tile: 64 rows x 256
#pragma unroll
        for (int i = 0; i < 8; ++i) {
            int flat = i * 256 + tid;
            int r = flat >> 5, c8 = (flat & 31) << 3;
            *reinterpret_cast<f16x8*>(ksm + r * 264 + c8) =
                *reinterpret_cast<const f16x8*>(kb + base + (size_t)(k0 + r) * Cc + c8);
        }
        // stage V^T tile: 256 rows x 64
#pragma unroll
        for (int i = 0; i < 8; ++i) {
            int flat = i * 256 + tid;
            int r = flat >> 3, c8 = (flat & 7) << 3;
            *reinterpret_cast<f16x8*>(vts + r * 72 + c8) =
                *reinterpret_cast<const f16x8*>(vtb + base + (size_t)r * Tt + k0 + c8);
        }
        __syncthreads();

        // S = Q K^T  (16 x 64 per wave; 4 col-blocks)
        f32x4 s[4] = {};
#pragma unroll
        for (int kc = 0; kc < 8; ++kc) {
            const int c0 = kc * 32 + lg * 8;
#pragma unroll
            for (int cb = 0; cb < 4; ++cb) {
                f16x8 kf = *reinterpret_cast<const f16x8*>(ksm + (cb * 16 + lr) * 264 + c0);
                s[cb] = MFMA(qf[kc], kf, s[cb]);
            }
        }

        // mask columns (mask==0 -> -1e30; the +1.0-where-mask==1 quirk cancels in softmax)
#pragma unroll
        for (int cb = 0; cb < 4; ++cb) {
            int mk = mask[(size_t)b * Tt + k0 + cb * 16 + lr];
            if (mk == 0) {
                s[cb][0] = -1e30f; s[cb][1] = -1e30f;
                s[cb][2] = -1e30f; s[cb][3] = -1e30f;
            }
        }

        // online softmax; lane's reg r holds row (lg*4+r), col (lane&15)
        float corr[4];
#pragma unroll
        for (int r = 0; r < 4; ++r) {
            float tm = fmaxf(fmaxf(s[0][r], s[1][r]), fmaxf(s[2][r], s[3][r]));
#pragma unroll
            for (int off = 1; off < 16; off <<= 1)
                tm = fmaxf(tm, __shfl_xor(tm, off, 64));
            float mn = fmaxf(m_run[r], tm);
            corr[r] = __expf(m_run[r] - mn);
            m_run[r] = mn;
            float rs = 0.f;
#pragma unroll
            for (int cb = 0; cb < 4; ++cb) {
                float p = __expf(s[cb][r] - mn);
                s[cb][r] = p;
                rs += p;
            }
#pragma unroll
            for (int off = 1; off < 16; off <<= 1)
                rs += __shfl_xor(rs, off, 64);
            l_run[r] = l_run[r] * corr[r] + rs;
        }
#pragma unroll
        for (int db = 0; db < 16; ++db) {
            o[db][0] *= corr[0]; o[db][1] *= corr[1];
            o[db][2] *= corr[2]; o[db][3] *= corr[3];
        }

        // P (f32, D-layout) -> f16 -> LDS [row][key] for A-layout reread
        _Float16* pw = ps + w * 16 * 72;
#pragma unroll
        for (int cb = 0; cb < 4; ++cb)
#pragma unroll
            for (int r = 0; r < 4; ++r)
                pw[(lg * 4 + r) * 72 + cb * 16 + lr] = (_Float16)s[cb][r];

        f16x8 pf[2];
#pragma unroll
        for (int kk = 0; kk < 2; ++kk)
            pf[kk] = *reinterpret_cast<const f16x8*>(pw + lr * 72 + kk * 32 + lg * 8);

        // O += P V   (B-frag: lane&15 = d col, contiguous keys from V^T rows)
#pragma unroll
        for (int db = 0; db < 16; ++db) {
#pragma unroll
            for (int kk = 0; kk < 2; ++kk) {
                f16x8 vf = *reinterpret_cast<const f16x8*>(vts + (db * 16 + lr) * 72 + kk * 32 + lg * 8);
                o[db] = MFMA(pf[kk], vf, o[db]);
            }
        }
    }

    float inv[4];
#pragma unroll
    for (int r = 0; r < 4; ++r) inv[r] = 1.f / l_run[r];
#pragma unroll
    for (int db = 0; db < 16; ++db)
#pragma unroll
        for (int r = 0; r < 4; ++r) {
            int tq = q0 + w * 16 + lg * 4 + r;
            int d  = db * 16 + lr;
            out[base + (size_t)tq * Cc + d] = o[db][r] * inv[r];
        }
}

extern "C" void kernel_launch(void* const* d_in, const int* in_sizes, int n_in,
                              void* d_out, int out_size, void* d_ws, size_t ws_size,
                              hipStream_t stream)
{
    (void)in_sizes; (void)n_in; (void)out_size; (void)ws_size;
    const float* x   = (const float*)d_in[0];
    const int*  mask = (const int*)d_in[1];
    const float* Wk  = (const float*)d_in[2];
    const float* Wq  = (const float*)d_in[3];
    const float* Wv  = (const float*)d_in[4];
    float* out = (float*)d_out;

    _Float16* q  = (_Float16*)d_ws;
    _Float16* k  = q + (size_t)BT * Cc;
    _Float16* vt = k + (size_t)BT * Cc;

    dim3 gA(128, 6), blk(256);
    size_t ldsA = (size_t)(128 + 128) * 264 * sizeof(_Float16);
    qkv_proj<<<gA, blk, ldsA, stream>>>(x, Wq, Wk, Wv, q, k, vt);

    dim3 gB(Tt / 64, Bb);
    size_t ldsB = (size_t)(64 * 264 + 256 * 72 + 4 * 16 * 72) * sizeof(_Float16);
    attn_kernel<<<gB, blk, ldsB, stream>>>(q, k, vt, mask, out);
}

// Round 3
// 218.378 us; speedup vs baseline: 1.0758x; 1.0758x over previous
//
#include <hip/hip_runtime.h>

// Round 3: swapped-operand flash attention + reg-prefetch pipeline + XCD batch locality.
//   (round 2 + cvt_pkrtz compile fix: scalar f32->f16 casts into P buffer)
//   d_in: 0=x [4,4096,256] f32, 1=mask [4,4096] i32, 2=Wk, 3=Wq, 4=Wv [256,256] f32
//   out: [4,4096,256] f32
// ws: q f16 [B*T][C] (pre-scaled 1/16), k f16 [B*T][C], vt f16 [B][C][T]

typedef __attribute__((ext_vector_type(8))) _Float16 f16x8;
typedef __attribute__((ext_vector_type(4))) _Float16 f16x4;
typedef __attribute__((ext_vector_type(4))) float    f32x4;

constexpr int Bb = 4;
constexpr int Tt = 4096;
constexpr int Cc = 256;
constexpr int BT = Bb * Tt;

#define MFMA(a, b, c) __builtin_amdgcn_mfma_f32_16x16x32_f16((a), (b), (c), 0, 0, 0)

// ---------------- Kernel A: fused QKV projection (y = x @ W^T) ----------------
__global__ __launch_bounds__(256) void qkv_proj(
    const float* __restrict__ x,
    const float* __restrict__ Wq, const float* __restrict__ Wk,
    const float* __restrict__ Wv,
    _Float16* __restrict__ qo, _Float16* __restrict__ ko,
    _Float16* __restrict__ vto)
{
    extern __shared__ _Float16 sm[];
    _Float16* xs = sm;              // [128][264]
    _Float16* wsm = sm + 128 * 264; // [128][264]

    const int tid = threadIdx.x;
    const int m0  = blockIdx.x * 128;
    const int ny  = blockIdx.y;
    const int mat = ny >> 1;              // 0=q 1=k 2=v
    const int d0  = (ny & 1) * 128;
    const float* W = (mat == 0) ? Wq : (mat == 1 ? Wk : Wv);

#pragma unroll
    for (int i = 0; i < 32; ++i) {
        int flat = i * 256 + tid;
        int r = flat >> 6, c4 = (flat & 63) << 2;
        float4 v = *reinterpret_cast<const float4*>(x + (size_t)(m0 + r) * Cc + c4);
        f16x4 h = { (_Float16)v.x, (_Float16)v.y, (_Float16)v.z, (_Float16)v.w };
        *reinterpret_cast<f16x4*>(xs + r * 264 + c4) = h;
    }
#pragma unroll
    for (int i = 0; i < 32; ++i) {
        int flat = i * 256 + tid;
        int r = flat >> 6, c4 = (flat & 63) << 2;
        float4 v = *reinterpret_cast<const float4*>(W + (size_t)(d0 + r) * Cc + c4);
        f16x4 h = { (_Float16)v.x, (_Float16)v.y, (_Float16)v.z, (_Float16)v.w };
        *reinterpret_cast<f16x4*>(wsm + r * 264 + c4) = h;
    }
    __syncthreads();

    const int w = tid >> 6, lane = tid & 63;
    const int lr = lane & 15, lg = lane >> 4;

    f32x4 acc[2][8] = {};

#pragma unroll
    for (int kc = 0; kc < 8; ++kc) {
        const int c0 = kc * 32 + lg * 8;
        f16x8 xf[2], wf[8];
#pragma unroll
        for (int mb = 0; mb < 2; ++mb)
            xf[mb] = *reinterpret_cast<const f16x8*>(xs + (w * 32 + mb * 16 + lr) * 264 + c0);
#pragma unroll
        for (int db = 0; db < 8; ++db)
            wf[db] = *reinterpret_cast<const f16x8*>(wsm + (db * 16 + lr) * 264 + c0);
        if (mat != 2) {
#pragma unroll
            for (int mb = 0; mb < 2; ++mb)
#pragma unroll
                for (int db = 0; db < 8; ++db)
                    acc[mb][db] = MFMA(wf[db], xf[mb], acc[mb][db]);
        } else {
#pragma unroll
            for (int mb = 0; mb < 2; ++mb)
#pragma unroll
                for (int db = 0; db < 8; ++db)
                    acc[mb][db] = MFMA(xf[mb], wf[db], acc[mb][db]);
        }
    }

    if (mat != 2) {
        const float sc = (mat == 0) ? 0.0625f : 1.0f;
        _Float16* dst = (mat == 0) ? qo : ko;
#pragma unroll
        for (int mb = 0; mb < 2; ++mb)
#pragma unroll
            for (int db = 0; db < 8; ++db) {
                int m = m0 + w * 32 + mb * 16 + lr;
                int d = d0 + db * 16 + lg * 4;
                f32x4 a = acc[mb][db];
                f16x4 h = { (_Float16)(a.x * sc), (_Float16)(a.y * sc),
                            (_Float16)(a.z * sc), (_Float16)(a.w * sc) };
                *reinterpret_cast<f16x4*>(dst + (size_t)m * Cc + d) = h;
            }
    } else {
#pragma unroll
        for (int mb = 0; mb < 2; ++mb)
#pragma unroll
            for (int db = 0; db < 8; ++db) {
                int d = d0 + db * 16 + lr;
                int m = m0 + w * 32 + mb * 16 + lg * 4;
                int bb = m >> 12, t = m & (Tt - 1);
                f32x4 a = acc[mb][db];
                f16x4 h = { (_Float16)a.x, (_Float16)a.y, (_Float16)a.z, (_Float16)a.w };
                *reinterpret_cast<f16x4*>(vto + (size_t)bb * Cc * Tt + (size_t)d * Tt + t) = h;
            }
    }
}

// ---------------- Kernel B: flash attention, swapped operands ----------------
// grid 256 linear; remap so batch b lives on XCD pair {2b,2b+1} (L2-resident K/V).
// 4 waves; wave owns 16 q rows (q = lane&15 within wave tile); key tiles of 64.
__global__ __launch_bounds__(256, 1) void attn_kernel(
    const _Float16* __restrict__ qb, const _Float16* __restrict__ kb,
    const _Float16* __restrict__ vtb, const int* __restrict__ mask,
    float* __restrict__ outp)
{
    extern __shared__ _Float16 sm[];
    _Float16* ksm = sm;                  // [64][264]  K tile (pad 8)
    _Float16* vts = sm + 64 * 264;       // [256][72]  V^T tile (pad 8)
    _Float16* pq  = vts + 256 * 72;      // [4][16][72] per-wave P buffer
    float*    smM = (float*)(pq + 4 * 16 * 72); // [64] mask bias

    const int tid = threadIdx.x, w = tid >> 6, lane = tid & 63;
    const int lr = lane & 15, lg = lane >> 4;

    // XCD-aware remap: bid%8 = XCD; batch = XCD>>1 (bijective over 256 blocks)
    const int bid = blockIdx.x;
    const int b   = (bid & 7) >> 1;
    const int qt  = ((bid >> 3) << 1) | (bid & 1);
    const int q0  = qt * 64;
    const size_t base = (size_t)b * Tt * Cc;

    // Q fragments (lane data: Q[q=lr][c=kc*32+lg*8+j]) — used as B-operand
    f16x8 qf[8];
    {
        const _Float16* qp = qb + base + (size_t)(q0 + w * 16 + lr) * Cc;
#pragma unroll
        for (int kc = 0; kc < 8; ++kc)
            qf[kc] = *reinterpret_cast<const f16x8*>(qp + kc * 32 + lg * 8);
    }

    f32x4 o[16] = {};             // O^T: o[db][r] = O[q=lr][d=db*16+lg*4+r]
    float m_run = -1e30f, l_run = 0.f;

    // staging decomposition (256 threads)
    const int krow = tid >> 5, kcol = (tid & 31) << 3;   // K rows i*8+krow
    const int vrow = tid >> 3, vcol = (tid & 7) << 3;    // V rows i*32+vrow

    f16x8 kreg[8], vreg[8];
    float mreg = 0.f;

    auto LOAD = [&](int k0) {
#pragma unroll
        for (int i = 0; i < 8; ++i)
            kreg[i] = *reinterpret_cast<const f16x8*>(
                kb + base + (size_t)(k0 + i * 8 + krow) * Cc + kcol);
#pragma unroll
        for (int i = 0; i < 8; ++i)
            vreg[i] = *reinterpret_cast<const f16x8*>(
                vtb + base + (size_t)(i * 32 + vrow) * Tt + k0 + vcol);
        if (tid < 64)
            mreg = (mask[(size_t)b * Tt + k0 + tid] == 0) ? -1e30f : 0.0f;
    };
    auto STORE = [&]() {
#pragma unroll
        for (int i = 0; i < 8; ++i)
            *reinterpret_cast<f16x8*>(ksm + (i * 8 + krow) * 264 + kcol) = kreg[i];
#pragma unroll
        for (int i = 0; i < 8; ++i)
            *reinterpret_cast<f16x8*>(vts + (i * 32 + vrow) * 72 + vcol) = vreg[i];
        if (tid < 64) smM[tid] = mreg;
    };

    LOAD(0);
    STORE();
    __syncthreads();

    _Float16* pw = pq + w * 16 * 72;

#pragma unroll 1
    for (int kt = 0; kt < 64; ++kt) {
        if (kt < 63) LOAD((kt + 1) * 64);   // prefetch into regs (flies during compute)

        // S^T = K Q^T : D[k=cb*16+lg*4+r][q=lr]
        f32x4 s4[4] = {};
#pragma unroll
        for (int kc = 0; kc < 8; ++kc) {
            const int c0 = kc * 32 + lg * 8;
#pragma unroll
            for (int cb = 0; cb < 4; ++cb) {
                f16x8 kf = *reinterpret_cast<const f16x8*>(ksm + (cb * 16 + lr) * 264 + c0);
                s4[cb] = MFMA(kf, qf[kc], s4[cb]);
            }
        }

        // mask bias (per k column)
#pragma unroll
        for (int cb = 0; cb < 4; ++cb)
#pragma unroll
            for (int r = 0; r < 4; ++r)
                s4[cb][r] += smM[cb * 16 + lg * 4 + r];

        // lane-local online softmax (this lane's q = lr; 16 k-values in regs)
        float a0 = fmaxf(fmaxf(s4[0][0], s4[0][1]), fmaxf(s4[0][2], s4[0][3]));
        float a1 = fmaxf(fmaxf(s4[1][0], s4[1][1]), fmaxf(s4[1][2], s4[1][3]));
        float a2 = fmaxf(fmaxf(s4[2][0], s4[2][1]), fmaxf(s4[2][2], s4[2][3]));
        float a3 = fmaxf(fmaxf(s4[3][0], s4[3][1]), fmaxf(s4[3][2], s4[3][3]));
        float tmax = fmaxf(fmaxf(a0, a1), fmaxf(a2, a3));
        tmax = fmaxf(tmax, __shfl_xor(tmax, 16, 64));
        tmax = fmaxf(tmax, __shfl_xor(tmax, 32, 64));
        float mn   = fmaxf(m_run, tmax);
        float corr = __expf(m_run - mn);
        m_run = mn;

        float rs = 0.f;
#pragma unroll
        for (int cb = 0; cb < 4; ++cb) {
#pragma unroll
            for (int r = 0; r < 4; ++r) {
                float p = __expf(s4[cb][r] - mn);
                s4[cb][r] = p;
                rs += p;
            }
        }
        rs += __shfl_xor(rs, 16, 64);
        rs += __shfl_xor(rs, 32, 64);
        l_run = l_run * corr + rs;

#pragma unroll
        for (int db = 0; db < 16; ++db) o[db] *= corr;

        // P^T[k][q=lr] -> f16 -> pq[q=lr][k] for B-operand reread
#pragma unroll
        for (int cb = 0; cb < 4; ++cb) {
            f16x4 h = { (_Float16)s4[cb][0], (_Float16)s4[cb][1],
                        (_Float16)s4[cb][2], (_Float16)s4[cb][3] };
            *reinterpret_cast<f16x4*>(pw + lr * 72 + cb * 16 + lg * 4) = h;
        }
        f16x8 pf0 = *reinterpret_cast<const f16x8*>(pw + lr * 72 + lg * 8);
        f16x8 pf1 = *reinterpret_cast<const f16x8*>(pw + lr * 72 + 32 + lg * 8);

        // O^T += V^T P^T : D[d=db*16+lg*4+r][q=lr]
#pragma unroll
        for (int db = 0; db < 16; ++db) {
            f16x8 vf0 = *reinterpret_cast<const f16x8*>(vts + (db * 16 + lr) * 72 + lg * 8);
            o[db] = MFMA(vf0, pf0, o[db]);
            f16x8 vf1 = *reinterpret_cast<const f16x8*>(vts + (db * 16 + lr) * 72 + 32 + lg * 8);
            o[db] = MFMA(vf1, pf1, o[db]);
        }

        __syncthreads();          // all waves done reading LDS tile kt
        if (kt < 63) STORE();     // regs (arrived during compute) -> LDS
        __syncthreads();
    }

    // epilogue: transpose O^T -> O through per-wave LDS, coalesced f32x4 stores
    const float invl = 1.0f / l_run;
    float* osm = reinterpret_cast<float*>(sm) + w * (256 * 17);  // [256 d][17] per wave
#pragma unroll
    for (int db = 0; db < 16; ++db)
#pragma unroll
        for (int r = 0; r < 4; ++r)
            osm[(db * 16 + lg * 4 + r) * 17 + lr] = o[db][r] * invl;
    // per-wave buffer: in-wave RAW ordered by lgkmcnt (compiler-inserted)
#pragma unroll
    for (int q = 0; q < 16; ++q) {
        f32x4 val;
#pragma unroll
        for (int i = 0; i < 4; ++i) val[i] = osm[(lane * 4 + i) * 17 + q];
        *reinterpret_cast<f32x4*>(outp + base + (size_t)(q0 + w * 16 + q) * Cc + lane * 4) = val;
    }
}

extern "C" void kernel_launch(void* const* d_in, const int* in_sizes, int n_in,
                              void* d_out, int out_size, void* d_ws, size_t ws_size,
                              hipStream_t stream)
{
    (void)in_sizes; (void)n_in; (void)out_size; (void)ws_size;
    const float* x   = (const float*)d_in[0];
    const int*  mask = (const int*)d_in[1];
    const float* Wk  = (const float*)d_in[2];
    const float* Wq  = (const float*)d_in[3];
    const float* Wv  = (const float*)d_in[4];
    float* out = (float*)d_out;

    _Float16* q  = (_Float16*)d_ws;
    _Float16* k  = q + (size_t)BT * Cc;
    _Float16* vt = k + (size_t)BT * Cc;

    dim3 gA(128, 6), blk(256);
    size_t ldsA = (size_t)(128 + 128) * 264 * sizeof(_Float16);
    qkv_proj<<<gA, blk, ldsA, stream>>>(x, Wq, Wk, Wv, q, k, vt);

    dim3 gB(256);
    size_t ldsB = (size_t)(64 * 264 + 256 * 72 + 4 * 16 * 72) * sizeof(_Float16)
                + 64 * sizeof(float);
    attn_kernel<<<gB, blk, ldsB, stream>>>(q, k, vt, mask, out);
}

// Round 4
// 186.502 us; speedup vs baseline: 1.2596x; 1.1709x over previous
//
#include <hip/hip_runtime.h>

// Round 4: split-K flash attention, grid 512 (2 blocks/CU), conflict-free LDS,
//          defer-max, setprio. QBLK=32 (2 q-subtiles x 2 k-groups), KVBLK=32.
//   d_in: 0=x [4,4096,256] f32, 1=mask [4,4096] i32, 2=Wk, 3=Wq, 4=Wv [256,256] f32
//   out: [4,4096,256] f32
// ws: q f16 [B*T][C] (pre-scaled 1/16), k f16 [B*T][C], vt f16 [B][C][T]

typedef __attribute__((ext_vector_type(8))) _Float16 f16x8;
typedef __attribute__((ext_vector_type(4))) _Float16 f16x4;
typedef __attribute__((ext_vector_type(4))) float    f32x4;

constexpr int Bb = 4;
constexpr int Tt = 4096;
constexpr int Cc = 256;
constexpr int BT = Bb * Tt;
constexpr int KV = 32;          // keys per tile per k-group
constexpr int NI = 64;          // tiles per k-group (T / (KV*2))

#define MFMA(a, b, c) __builtin_amdgcn_mfma_f32_16x16x32_f16((a), (b), (c), 0, 0, 0)

// ---------------- Kernel A: fused QKV projection (y = x @ W^T) ----------------
__global__ __launch_bounds__(256) void qkv_proj(
    const float* __restrict__ x,
    const float* __restrict__ Wq, const float* __restrict__ Wk,
    const float* __restrict__ Wv,
    _Float16* __restrict__ qo, _Float16* __restrict__ ko,
    _Float16* __restrict__ vto)
{
    extern __shared__ _Float16 sm[];
    _Float16* xs = sm;              // [128][264]
    _Float16* wsm = sm + 128 * 264; // [128][264]

    const int tid = threadIdx.x;
    const int m0  = blockIdx.x * 128;
    const int ny  = blockIdx.y;
    const int mat = ny >> 1;              // 0=q 1=k 2=v
    const int d0  = (ny & 1) * 128;
    const float* W = (mat == 0) ? Wq : (mat == 1 ? Wk : Wv);

#pragma unroll
    for (int i = 0; i < 32; ++i) {
        int flat = i * 256 + tid;
        int r = flat >> 6, c4 = (flat & 63) << 2;
        float4 v = *reinterpret_cast<const float4*>(x + (size_t)(m0 + r) * Cc + c4);
        f16x4 h = { (_Float16)v.x, (_Float16)v.y, (_Float16)v.z, (_Float16)v.w };
        *reinterpret_cast<f16x4*>(xs + r * 264 + c4) = h;
    }
#pragma unroll
    for (int i = 0; i < 32; ++i) {
        int flat = i * 256 + tid;
        int r = flat >> 6, c4 = (flat & 63) << 2;
        float4 v = *reinterpret_cast<const float4*>(W + (size_t)(d0 + r) * Cc + c4);
        f16x4 h = { (_Float16)v.x, (_Float16)v.y, (_Float16)v.z, (_Float16)v.w };
        *reinterpret_cast<f16x4*>(wsm + r * 264 + c4) = h;
    }
    __syncthreads();

    const int w = tid >> 6, lane = tid & 63;
    const int lr = lane & 15, lg = lane >> 4;

    f32x4 acc[2][8] = {};

#pragma unroll
    for (int kc = 0; kc < 8; ++kc) {
        const int c0 = kc * 32 + lg * 8;
        f16x8 xf[2], wf[8];
#pragma unroll
        for (int mb = 0; mb < 2; ++mb)
            xf[mb] = *reinterpret_cast<const f16x8*>(xs + (w * 32 + mb * 16 + lr) * 264 + c0);
#pragma unroll
        for (int db = 0; db < 8; ++db)
            wf[db] = *reinterpret_cast<const f16x8*>(wsm + (db * 16 + lr) * 264 + c0);
        if (mat != 2) {
#pragma unroll
            for (int mb = 0; mb < 2; ++mb)
#pragma unroll
                for (int db = 0; db < 8; ++db)
                    acc[mb][db] = MFMA(wf[db], xf[mb], acc[mb][db]);
        } else {
#pragma unroll
            for (int mb = 0; mb < 2; ++mb)
#pragma unroll
                for (int db = 0; db < 8; ++db)
                    acc[mb][db] = MFMA(xf[mb], wf[db], acc[mb][db]);
        }
    }

    if (mat != 2) {
        const float sc = (mat == 0) ? 0.0625f : 1.0f;
        _Float16* dst = (mat == 0) ? qo : ko;
#pragma unroll
        for (int mb = 0; mb < 2; ++mb)
#pragma unroll
            for (int db = 0; db < 8; ++db) {
                int m = m0 + w * 32 + mb * 16 + lr;
                int d = d0 + db * 16 + lg * 4;
                f32x4 a = acc[mb][db];
                f16x4 h = { (_Float16)(a.x * sc), (_Float16)(a.y * sc),
                            (_Float16)(a.z * sc), (_Float16)(a.w * sc) };
                *reinterpret_cast<f16x4*>(dst + (size_t)m * Cc + d) = h;
            }
    } else {
#pragma unroll
        for (int mb = 0; mb < 2; ++mb)
#pragma unroll
            for (int db = 0; db < 8; ++db) {
                int d = d0 + db * 16 + lr;
                int m = m0 + w * 32 + mb * 16 + lg * 4;
                int bb = m >> 12, t = m & (Tt - 1);
                f32x4 a = acc[mb][db];
                f16x4 h = { (_Float16)a.x, (_Float16)a.y, (_Float16)a.z, (_Float16)a.w };
                *reinterpret_cast<f16x4*>(vto + (size_t)bb * Cc * Tt + (size_t)d * Tt + t) = h;
            }
    }
}

// ---------------- Kernel B: split-K flash attention ----------------
// grid 512; bid%8 = XCD, batch = XCD>>1 (each XCD's L2 holds one batch's K/V).
// 4 waves: w = g*2+qs?? -> g = w>>1 (k-group), qs = w&1 (q-subtile of 16 rows).
// LDS (halves): ksm [2][32][264]=16896 | vts [2][256][32] swz =16384 | pq [4][16][40]=2560
//               smM [2][32] floats after. Total 71936 B -> 2 blocks/CU.
__global__ __launch_bounds__(256, 2) void attn_kernel(
    const _Float16* __restrict__ qb, const _Float16* __restrict__ kb,
    const _Float16* __restrict__ vtb, const int* __restrict__ mask,
    float* __restrict__ outp)
{
    extern __shared__ _Float16 sm[];
    _Float16* ksm = sm;                  // [2][32][264]
    _Float16* vts = sm + 16896;          // [2][256][32], chunk-XOR swizzled
    _Float16* pq  = sm + 33280;          // [4][16][40]
    float*    smM = (float*)(sm + 35840);// [2][32]

    const int tid = threadIdx.x, w = tid >> 6, lane = tid & 63;
    const int lr = lane & 15, lg = lane >> 4;
    const int g = w >> 1, qs = w & 1;
    const int ht = tid & 127;            // thread id within k-group half (tid>>7 == g)

    const int bid = blockIdx.x;
    const int b   = (bid & 7) >> 1;
    const int qt  = ((bid >> 3) << 1) | (bid & 1);   // [0,128)
    const int q0  = qt * 32;
    const size_t base = (size_t)b * Tt * Cc;

    // Q fragments for this wave's 16 q-rows (B-operand: q=lr, col=kc*32+lg*8+j)
    f16x8 qf[8];
    {
        const _Float16* qp = qb + base + (size_t)(q0 + qs * 16 + lr) * Cc;
#pragma unroll
        for (int kc = 0; kc < 8; ++kc)
            qf[kc] = *reinterpret_cast<const f16x8*>(qp + kc * 32 + lg * 8);
    }

    f32x4 o[16] = {};                 // o[db][r] = O[q=lr][d=db*16+lg*4+r]
    float m_run = -60.f, l_run = 0.f; // -60: real logits always trigger first update

    _Float16* kbuf = ksm + g * (32 * 264);
    _Float16* vbuf = vts + g * (256 * 32);

    f16x8 kreg[8], vreg[8];
    float mreg = 0.f;

    auto LOAD = [&](int k0) {
#pragma unroll
        for (int j = 0; j < 8; ++j) {
            int f = j * 128 + ht, r = f >> 5, c = (f & 31) << 3;
            kreg[j] = *reinterpret_cast<const f16x8*>(
                kb + base + (size_t)(k0 + r) * Cc + c);
        }
#pragma unroll
        for (int j = 0; j < 8; ++j) {
            int f = j * 128 + ht, r = f >> 2, c = (f & 3) << 3;
            vreg[j] = *reinterpret_cast<const f16x8*>(
                vtb + base + (size_t)r * Tt + k0 + c);
        }
        if (ht < 32)
            mreg = (mask[(size_t)b * Tt + k0 + ht] == 0) ? -1e30f : 0.0f;
    };
    auto STORE = [&]() {
#pragma unroll
        for (int j = 0; j < 8; ++j) {
            int f = j * 128 + ht, r = f >> 5, c = (f & 31) << 3;
            *reinterpret_cast<f16x8*>(kbuf + r * 264 + c) = kreg[j];
        }
#pragma unroll
        for (int j = 0; j < 8; ++j) {
            int f = j * 128 + ht, r = f >> 2, ch = f & 3;
            int cp = ch ^ ((r >> 1) & 3);               // bank-spread chunk swizzle
            *reinterpret_cast<f16x8*>(vbuf + r * 32 + cp * 8) = vreg[j];
        }
        if (ht < 32) smM[g * 32 + ht] = mreg;
    };

    LOAD(g * KV);
    STORE();
    __syncthreads();

    _Float16* pw = pq + w * (16 * 40);
    const int vchunk = lg ^ ((lr >> 1) & 3);            // PV read swizzle (row=db*16+lr)

#pragma unroll 1
    for (int i = 0; i < NI; ++i) {
        if (i < NI - 1) LOAD((2 * (i + 1) + g) * KV);   // reg prefetch

        // S^T = K Q^T : D[k=cb*16+lg*4+r][q=lr]
        f32x4 s4[2] = {};
        __builtin_amdgcn_s_setprio(1);
#pragma unroll
        for (int kc = 0; kc < 8; ++kc) {
            const int c0 = kc * 32 + lg * 8;
#pragma unroll
            for (int cb = 0; cb < 2; ++cb) {
                f16x8 kf = *reinterpret_cast<const f16x8*>(kbuf + (cb * 16 + lr) * 264 + c0);
                s4[cb] = MFMA(kf, qf[kc], s4[cb]);
            }
        }
        __builtin_amdgcn_s_setprio(0);

#pragma unroll
        for (int cb = 0; cb < 2; ++cb)
#pragma unroll
            for (int r = 0; r < 4; ++r)
                s4[cb][r] += smM[g * 32 + cb * 16 + lg * 4 + r];

        // lane-local softmax (q=lr); reduce across lg groups only
        float a0 = fmaxf(fmaxf(s4[0][0], s4[0][1]), fmaxf(s4[0][2], s4[0][3]));
        float a1 = fmaxf(fmaxf(s4[1][0], s4[1][1]), fmaxf(s4[1][2], s4[1][3]));
        float tmax = fmaxf(a0, a1);
        tmax = fmaxf(tmax, __shfl_xor(tmax, 16, 64));
        tmax = fmaxf(tmax, __shfl_xor(tmax, 32, 64));

        if (__any(tmax > m_run + 8.f)) {   // defer-max: rescale only on real growth
            float mn   = fmaxf(m_run, tmax);
            float corr = __expf(m_run - mn);
            m_run = mn;
            l_run *= corr;
#pragma unroll
            for (int db = 0; db < 16; ++db) o[db] *= corr;
        }

        float rs = 0.f;
#pragma unroll
        for (int cb = 0; cb < 2; ++cb)
#pragma unroll
            for (int r = 0; r < 4; ++r) {
                float p = __expf(s4[cb][r] - m_run);
                s4[cb][r] = p;
                rs += p;
            }
        rs += __shfl_xor(rs, 16, 64);
        rs += __shfl_xor(rs, 32, 64);
        l_run += rs;

        // P^T[k][q=lr] -> pq[q=lr][k] (f16), reread as B-operand
#pragma unroll
        for (int cb = 0; cb < 2; ++cb) {
            f16x4 h = { (_Float16)s4[cb][0], (_Float16)s4[cb][1],
                        (_Float16)s4[cb][2], (_Float16)s4[cb][3] };
            *reinterpret_cast<f16x4*>(pw + lr * 40 + cb * 16 + lg * 4) = h;
        }
        f16x8 pf = *reinterpret_cast<const f16x8*>(pw + lr * 40 + lg * 8);

        // O^T += V^T P^T
        __builtin_amdgcn_s_setprio(1);
#pragma unroll
        for (int db = 0; db < 16; ++db) {
            f16x8 vf = *reinterpret_cast<const f16x8*>(
                vbuf + (db * 16 + lr) * 32 + vchunk * 8);
            o[db] = MFMA(vf, pf, o[db]);
        }
        __builtin_amdgcn_s_setprio(0);

        __syncthreads();
        if (i < NI - 1) STORE();
        __syncthreads();
    }

    // ---- merge k-groups + coalesced store ----
    float* oex = (float*)sm;                 // [2][256][17]
    float* mex = oex + 2 * 256 * 17;         // [4][16]
    float* lex = mex + 64;                   // [4][16]

    if (lg == 0) mex[w * 16 + lr] = m_run;
    __syncthreads();
    float mstar = fmaxf(m_run, mex[(w ^ 2) * 16 + lr]);
    float scale = __expf(m_run - mstar);
    float lsc   = l_run * scale;

    if (g == 1) {
        float* dst = oex + qs * (256 * 17);
#pragma unroll
        for (int db = 0; db < 16; ++db)
#pragma unroll
            for (int r = 0; r < 4; ++r)
                dst[(db * 16 + lg * 4 + r) * 17 + lr] = o[db][r] * scale;
        if (lg == 0) lex[w * 16 + lr] = lsc;
    }
    __syncthreads();
    if (g == 0) {
        float l_tot = lsc + lex[(2 + qs) * 16 + lr];
        float invl  = 1.f / l_tot;
        float* buf  = oex + qs * (256 * 17);
#pragma unroll
        for (int db = 0; db < 16; ++db)
#pragma unroll
            for (int r = 0; r < 4; ++r) {
                int idx = (db * 16 + lg * 4 + r) * 17 + lr;
                buf[idx] = (o[db][r] * scale + buf[idx]) * invl;
            }
#pragma unroll
        for (int q = 0; q < 16; ++q) {
            f32x4 val;
#pragma unroll
            for (int i = 0; i < 4; ++i) val[i] = buf[(lane * 4 + i) * 17 + q];
            *reinterpret_cast<f32x4*>(
                outp + base + (size_t)(q0 + qs * 16 + q) * Cc + lane * 4) = val;
        }
    }
}

extern "C" void kernel_launch(void* const* d_in, const int* in_sizes, int n_in,
                              void* d_out, int out_size, void* d_ws, size_t ws_size,
                              hipStream_t stream)
{
    (void)in_sizes; (void)n_in; (void)out_size; (void)ws_size;
    const float* x   = (const float*)d_in[0];
    const int*  mask = (const int*)d_in[1];
    const float* Wk  = (const float*)d_in[2];
    const float* Wq  = (const float*)d_in[3];
    const float* Wv  = (const float*)d_in[4];
    float* out = (float*)d_out;

    _Float16* q  = (_Float16*)d_ws;
    _Float16* k  = q + (size_t)BT * Cc;
    _Float16* vt = k + (size_t)BT * Cc;

    dim3 gA(128, 6), blk(256);
    size_t ldsA = (size_t)(128 + 128) * 264 * sizeof(_Float16);
    qkv_proj<<<gA, blk, ldsA, stream>>>(x, Wq, Wk, Wv, q, k, vt);

    dim3 gB(512);
    size_t ldsB = 35840 * sizeof(_Float16) + 64 * sizeof(float);  // 71936 B
    attn_kernel<<<gB, blk, ldsB, stream>>>(q, k, vt, mask, out);
}